// Round 7
// baseline (133.814 us; speedup 1.0000x reference)
//
#include <hip/hip_runtime.h>

// VectorQuantizer gfx950 R11: TRUE 16-waves/CU argmin (one 1024-thread block),
// waves split the CODE axis. Ledger: R5 (16 waves, 2x per-wave work) hurt;
// R8 (grid=2/CU) degenerated to two sequential 8-wave passes; so >2 waves/SIMD
// with constant per-CU work has never actually run. Here wave w handles
// row-group (w&7) (64 rows) x code-half (w>>3) (512 codes):
//  - per-CU MFMA (4096), LDS b128 reads (1024), VALU min-work: IDENTICAL to R4.
//  - new: duplicate A-frag x reads (L3-absorbed; FETCH=17MB proves x L3-res)
//    and 256 LDS atomicMin merges into keys[512].
//  - LDS 147.5 KB; __launch_bounds__(1024) -> 128-VGPR cap, body ~90, no spill.
// Phase-split retained from R10: argmin writes indices+SSE (packed-key s_rec +
// fp32 ||x||^2, loss err ~1e-6); vq_gather streams exact fp32 codebook rows.
// dist2[n,k] = ||x||^2 - 2 x.e_k + ||e_k||^2 ; argmin invariant to ||x||^2.
// MFMA C-init cc = 0.5 + ||e_k||^2 => s in [0.375,0.625] (>0 => IEEE bits
// order-monotonic). key = (bits(s) & ~1023) | code; argmin = v_min_u32.

typedef __attribute__((ext_vector_type(8))) short short8;
typedef __attribute__((ext_vector_type(4))) float f32x4;

#define VQ_D 64
#define MTILE 512   // rows per block (8 row-groups x 64 rows)
#define NTH 1024    // 16 waves
#define CSTRIDE 68  // ushorts per code row (64 data + 4 pad), padded in GLOBAL too
#define CHUNKS 8704 // 139264 B / 16

__device__ inline unsigned short f2bf(float f) {
  union { float f; unsigned u; } v; v.f = f;
  unsigned r = v.u + 0x7FFFu + ((v.u >> 16) & 1u);  // RNE
  return (unsigned short)(r >> 16);
}

// Prep: one wave per codebook row. c2b[k] = 0.5 + ||e_k||^2 ; codebook -> bf16
// in the PADDED stride-68 layout (zeroed pad) for the linear global_load_lds
// copy. Also zeroes the sse accumulator and completion counter.
__global__ __launch_bounds__(256) void vq_prep(const float* __restrict__ cb,
                                               float* __restrict__ c2b,
                                               unsigned short* __restrict__ cbb,
                                               float* __restrict__ sse,
                                               unsigned* __restrict__ counter, int K) {
  if (blockIdx.x == 0 && threadIdx.x == 0) { *sse = 0.f; *counter = 0u; }
  int w = (int)((blockIdx.x * 256 + threadIdx.x) >> 6);
  int lane = threadIdx.x & 63;
  if (w >= K) return;
  float v = cb[(size_t)w * VQ_D + lane];
  cbb[(size_t)w * CSTRIDE + lane] = f2bf(v);
  if (lane < CSTRIDE - VQ_D) cbb[(size_t)w * CSTRIDE + VQ_D + lane] = 0;
  float s = v * v;
#pragma unroll
  for (int off = 32; off; off >>= 1) s += __shfl_down(s, off);
  if (lane == 0) c2b[w] = s + 0.5f;
}

__global__ __launch_bounds__(NTH) void vq_argmin(
    const float* __restrict__ x, const float* __restrict__ c2b,
    const unsigned short* __restrict__ cbb, int* __restrict__ gidx,
    float* __restrict__ out, float* __restrict__ sse_out,
    unsigned* __restrict__ counter, int nblocks) {
  __shared__ unsigned short cbs[1024 * CSTRIDE];  // 139264 B
  __shared__ float c2s[1024];                     // 4096 B
  __shared__ unsigned keys[MTILE];                // 2048 B merged argmin keys
  __shared__ float xn[MTILE];                     // 2048 B fp32 ||x||^2 per row
  __shared__ float redbuf[8];

  const int tid = threadIdx.x;
  const int wave = tid >> 6;
  const int lane = tid & 63;
  const int quad = lane >> 4;
  const int col = lane & 15;
  const int rg = wave & 7;       // row-group: 64 rows
  const int half = wave >> 3;    // code-half: 512 codes
  const long blockRow0 = (long)blockIdx.x * MTILE;

  // ---- Stage padded bf16 codebook (8704 x 16B chunks) via global_load_lds:
  // wave-uniform LDS base + lane*16, per-lane global src. 9 iters of 1024.
  const char* gbase = (const char*)cbb;
#pragma unroll
  for (int i = 0; i < 9; ++i) {
    const int chunk0 = i * NTH + wave * 64;  // wave-uniform
    if (chunk0 < CHUNKS) {
      const char* src = gbase + (size_t)(chunk0 + lane) * 16;
      __builtin_amdgcn_global_load_lds(
          (const __attribute__((address_space(1))) void*)src,
          (__attribute__((address_space(3))) void*)(cbs + (size_t)chunk0 * 8),
          16, 0, 0);
    }
  }
  c2s[tid] = c2b[tid];
  if (tid < MTILE) keys[tid] = 0xFFFFFFFFu;

  // ---- A fragments: bf16(-2*x) (+ fp32 row norms in waves 0-7 only).
  // Lane(quad,col) holds dims [ks*32+quad*8,+8) of row rg*64 + mi*16 + col.
  short8 Af[4][2];
#pragma unroll
  for (int mi = 0; mi < 4; ++mi) {
    float nrm = 0.f;
#pragma unroll
    for (int ks = 0; ks < 2; ++ks) {
      long row = blockRow0 + rg * 64 + mi * 16 + col;
      const f32x4* xp = (const f32x4*)(x + row * VQ_D + ks * 32 + quad * 8);
      f32x4 lo = xp[0];
      f32x4 hi = xp[1];
      if (half == 0) {
        nrm += lo[0] * lo[0] + lo[1] * lo[1] + lo[2] * lo[2] + lo[3] * lo[3];
        nrm += hi[0] * hi[0] + hi[1] * hi[1] + hi[2] * hi[2] + hi[3] * hi[3];
      }
      short8 a;
      a[0] = (short)f2bf(-2.f * lo[0]); a[1] = (short)f2bf(-2.f * lo[1]);
      a[2] = (short)f2bf(-2.f * lo[2]); a[3] = (short)f2bf(-2.f * lo[3]);
      a[4] = (short)f2bf(-2.f * hi[0]); a[5] = (short)f2bf(-2.f * hi[1]);
      a[6] = (short)f2bf(-2.f * hi[2]); a[7] = (short)f2bf(-2.f * hi[3]);
      Af[mi][ks] = a;
    }
    if (half == 0) {
      nrm += __shfl_xor(nrm, 16);  // sum across the 4 quads (full 64-dim norm)
      nrm += __shfl_xor(nrm, 32);
      if (quad == 0) xn[rg * 64 + mi * 16 + col] = nrm;
    }
  }

  unsigned bk[4][4];
#pragma unroll
  for (int mi = 0; mi < 4; ++mi)
#pragma unroll
    for (int r = 0; r < 4; ++r) bk[mi][r] = 0xFFFFFFFFu;

  __syncthreads();  // codebook staged (vmcnt drained), keys/xn visible

  // ---- Barrier-free K-loop: 32 iters x 16 codes of this wave's half.
  const unsigned short* bbase = cbs + (size_t)(half * 512 + col) * CSTRIDE + quad * 8;
#pragma unroll 4
  for (int t = 0; t < 32; ++t) {
    const unsigned short* bp = bbase + t * 16 * CSTRIDE;
    short8 b0 = *(const short8*)bp;
    short8 b1 = *(const short8*)(bp + 32);
    float cc = c2s[half * 512 + t * 16 + col];

    f32x4 acc[4];
#pragma unroll
    for (int mi = 0; mi < 4; ++mi) {
      f32x4 a = {cc, cc, cc, cc};
      a = __builtin_amdgcn_mfma_f32_16x16x32_bf16(Af[mi][0], b0, a, 0, 0, 0);
      a = __builtin_amdgcn_mfma_f32_16x16x32_bf16(Af[mi][1], b1, a, 0, 0, 0);
      acc[mi] = a;
    }

    const unsigned code = (unsigned)(half * 512 + (t << 4) + col);
#pragma unroll
    for (int mi = 0; mi < 4; ++mi)
#pragma unroll
      for (int r = 0; r < 4; ++r)
        bk[mi][r] = min(bk[mi][r], (__float_as_uint(acc[mi][r]) & 0xFFFFFC00u) | code);
  }

  // ---- Reduce keys across the 16 columns of each quad group.
#pragma unroll
  for (int off = 1; off < 16; off <<= 1) {
#pragma unroll
    for (int mi = 0; mi < 4; ++mi)
#pragma unroll
      for (int r = 0; r < 4; ++r) {
        unsigned o = (unsigned)__shfl_xor((int)bk[mi][r], off);
        bk[mi][r] = min(bk[mi][r], o);
      }
  }
  // ---- Merge the two code-halves per row via LDS atomicMin.
  if (col == 0) {
#pragma unroll
    for (int mi = 0; mi < 4; ++mi)
#pragma unroll
      for (int r = 0; r < 4; ++r)
        atomicMin(&keys[rg * 64 + mi * 16 + quad * 4 + r], bk[mi][r]);
  }
  __syncthreads();

  // ---- Indices + SSE from the merged keys (threads 0..511 = waves 0..7).
  float sse = 0.f;
  if (tid < MTILE) {
    const unsigned k = keys[tid];
    gidx[blockRow0 + tid] = (int)(k & 1023u);
    const float s_rec = __uint_as_float(k & 0xFFFFFC00u);
    sse = s_rec - 0.5f + xn[tid];
#pragma unroll
    for (int off = 32; off; off >>= 1) sse += __shfl_down(sse, off);
    if (lane == 0) redbuf[wave] = sse;
  }
  __syncthreads();

  if (tid == 0) {
    float s = 0.f;
#pragma unroll
    for (int w = 0; w < 8; ++w) s += redbuf[w];
    atomicAdd(sse_out, s);
    __threadfence();
    unsigned old = atomicAdd(counter, 1u);
    if (old == (unsigned)(nblocks - 1)) {
      float tot = atomicAdd(sse_out, 0.f);
      long nelem = (long)nblocks * MTILE * VQ_D;
      out[nelem] = 1.25f * tot / (float)nelem;
    }
  }
}

// Pure streaming scatter: out row = exact fp32 codebook row. Full occupancy,
// no LDS; 16 consecutive threads share one idx (L1 broadcast); cb is 256 KB
// L2/L3-resident; 32 MB coalesced write.
__global__ __launch_bounds__(256) void vq_gather(const float* __restrict__ cb,
                                                 const int* __restrict__ gidx,
                                                 float* __restrict__ out) {
  const int t = blockIdx.x * 256 + threadIdx.x;  // 2^19 threads
  const f32x4* cb4 = (const f32x4*)cb;
  f32x4* out4 = (f32x4*)out;
#pragma unroll
  for (int i = 0; i < 4; ++i) {
    const int f = t + i * (1 << 19);  // 2^21 float4s total
    const int row = f >> 4;
    const int d4 = f & 15;
    out4[f] = cb4[(size_t)gidx[row] * 16 + d4];
  }
}

extern "C" void kernel_launch(void* const* d_in, const int* in_sizes, int n_in,
                              void* d_out, int out_size, void* d_ws, size_t ws_size,
                              hipStream_t stream) {
  const float* x = (const float*)d_in[0];
  const float* cb = (const float*)d_in[1];
  float* out = (float*)d_out;

  const long n_elem = (long)in_sizes[0];   // 8388608
  const int nrows = (int)(n_elem / VQ_D);  // 131072
  const int K = in_sizes[1] / VQ_D;        // 1024
  const int nblocks = nrows / MTILE;       // 256

  char* ws = (char*)d_ws;
  float* sse = (float*)ws;                             // 4 B
  unsigned* counter = (unsigned*)(ws + 64);            // 4 B
  float* c2b = (float*)(ws + 256);                     // 4 KB
  unsigned short* cbb = (unsigned short*)(ws + 8192);  // 139264 B padded bf16 codebook
  int* gidx = (int*)(ws + 8192 + 139264);              // 512 KB row indices

  vq_prep<<<dim3((K * 64 + 255) / 256), dim3(256), 0, stream>>>(cb, c2b, cbb, sse, counter, K);
  vq_argmin<<<dim3(nblocks), dim3(NTH), 0, stream>>>(x, c2b, cbb, gidx, out, sse, counter, nblocks);
  vq_gather<<<dim3(nrows * 16 / (256 * 4)), dim3(256), 0, stream>>>(cb, gidx, out);
}

// Round 8
// 128.628 us; speedup vs baseline: 1.0403x; 1.0403x over previous
//
#include <hip/hip_runtime.h>

// VectorQuantizer gfx950 R12: R10 base with the in-order-vmcnt serialization
// fixed + deeper K-loop unroll + nontemporal gather stores.
// R11 exonerated occupancy (37% occ, constant work -> SLOWER). R12 theory:
// vmcnt retires IN ISSUE ORDER, so R10's A-frag loads (issued after 17
// global_load_lds) could only be consumed after the full 139 KB staging
// drained -- stage/A-frag/K-loop were serial latency chains. Fix: issue the
// 16 A-frag dwordx4 loads FIRST, then c2s, then the 17 glls; the f2bf+norm
// VALU then overlaps the staging drain (barrier is the only join).
// Also: K-loop unroll 4->8 (VGPR budget 256 at 8 waves/CU; was using 88),
// and vq_gather uses hoisted idx loads + nontemporal f32x4 stores.
// dist2[n,k] = ||x||^2 - 2 x.e_k + ||e_k||^2 ; argmin invariant to ||x||^2.
// MFMA C-init cc = 0.5 + ||e_k||^2 => s in [0.375,0.625] (>0 => IEEE bits
// order-monotonic). key = (bits(s) & ~1023) | code; argmin = v_min_u32.
// SSE from packed key: dist2 = s_rec - 0.5 + ||x||^2 (loss err ~1e-6).

typedef __attribute__((ext_vector_type(8))) short short8;
typedef __attribute__((ext_vector_type(4))) float f32x4;

#define VQ_D 64
#define MTILE 512   // rows per block (8 waves x 64 rows)
#define NTH 512
#define CSTRIDE 68  // ushorts per code row (64 data + 4 pad), padded in GLOBAL too

__device__ inline unsigned short f2bf(float f) {
  union { float f; unsigned u; } v; v.f = f;
  unsigned r = v.u + 0x7FFFu + ((v.u >> 16) & 1u);  // RNE
  return (unsigned short)(r >> 16);
}

// Prep: one wave per codebook row. c2b[k] = 0.5 + ||e_k||^2 ; codebook -> bf16
// in the PADDED stride-68 layout (zeroed pad) for the linear global_load_lds
// copy. Also zeroes the sse accumulator and completion counter.
__global__ __launch_bounds__(256) void vq_prep(const float* __restrict__ cb,
                                               float* __restrict__ c2b,
                                               unsigned short* __restrict__ cbb,
                                               float* __restrict__ sse,
                                               unsigned* __restrict__ counter, int K) {
  if (blockIdx.x == 0 && threadIdx.x == 0) { *sse = 0.f; *counter = 0u; }
  int w = (int)((blockIdx.x * 256 + threadIdx.x) >> 6);
  int lane = threadIdx.x & 63;
  if (w >= K) return;
  float v = cb[(size_t)w * VQ_D + lane];
  cbb[(size_t)w * CSTRIDE + lane] = f2bf(v);
  if (lane < CSTRIDE - VQ_D) cbb[(size_t)w * CSTRIDE + VQ_D + lane] = 0;
  float s = v * v;
#pragma unroll
  for (int off = 32; off; off >>= 1) s += __shfl_down(s, off);
  if (lane == 0) c2b[w] = s + 0.5f;
}

__global__ __launch_bounds__(NTH) void vq_argmin(
    const float* __restrict__ x, const float* __restrict__ c2b,
    const unsigned short* __restrict__ cbb, int* __restrict__ gidx,
    float* __restrict__ out, float* __restrict__ sse_out,
    unsigned* __restrict__ counter, int nblocks) {
  __shared__ unsigned short cbs[1024 * CSTRIDE];  // 139264 B
  __shared__ float c2s[1024];                     // 4096 B
  __shared__ float xn[MTILE];                     // 2048 B fp32 ||x||^2 per row
  __shared__ float redbuf[8];

  const int tid = threadIdx.x;
  const int wave = tid >> 6;
  const int lane = tid & 63;
  const int quad = lane >> 4;
  const int col = lane & 15;
  const long blockRow0 = (long)blockIdx.x * MTILE;
  const int waveRow0 = wave * 64;

  // ---- ISSUE ORDER MATTERS (vmcnt is in-order): A-frag x loads FIRST, then
  // c2s, then the 17 global_load_lds. The f2bf/norm VALU below then only waits
  // for the A-loads (vmcnt drops to the gll count) and overlaps the staging
  // drain; __syncthreads is the only join with the staged codebook.
  f32x4 xr[4][2][2];
#pragma unroll
  for (int mi = 0; mi < 4; ++mi) {
#pragma unroll
    for (int ks = 0; ks < 2; ++ks) {
      long row = blockRow0 + waveRow0 + mi * 16 + col;
      const f32x4* xp = (const f32x4*)(x + row * VQ_D + ks * 32 + quad * 8);
      xr[mi][ks][0] = xp[0];
      xr[mi][ks][1] = xp[1];
    }
  }
  const float cc0 = c2b[tid];
  const float cc1 = c2b[tid + 512];

  const char* gbase = (const char*)cbb;
#pragma unroll
  for (int i = 0; i < 17; ++i) {
    const int chunk0 = i * NTH + wave * 64;  // wave-uniform
    const char* src = gbase + (size_t)(chunk0 + lane) * 16;
    __builtin_amdgcn_global_load_lds(
        (const __attribute__((address_space(1))) void*)src,
        (__attribute__((address_space(3))) void*)(cbs + (size_t)chunk0 * 8),
        16, 0, 0);
  }
  c2s[tid] = cc0;
  c2s[tid + 512] = cc1;

  // ---- A fragments: bf16(-2*x) + fp32 row norms (overlaps staging drain).
  short8 Af[4][2];
#pragma unroll
  for (int mi = 0; mi < 4; ++mi) {
    float nrm = 0.f;
#pragma unroll
    for (int ks = 0; ks < 2; ++ks) {
      f32x4 lo = xr[mi][ks][0];
      f32x4 hi = xr[mi][ks][1];
      nrm += lo[0] * lo[0] + lo[1] * lo[1] + lo[2] * lo[2] + lo[3] * lo[3];
      nrm += hi[0] * hi[0] + hi[1] * hi[1] + hi[2] * hi[2] + hi[3] * hi[3];
      short8 a;
      a[0] = (short)f2bf(-2.f * lo[0]); a[1] = (short)f2bf(-2.f * lo[1]);
      a[2] = (short)f2bf(-2.f * lo[2]); a[3] = (short)f2bf(-2.f * lo[3]);
      a[4] = (short)f2bf(-2.f * hi[0]); a[5] = (short)f2bf(-2.f * hi[1]);
      a[6] = (short)f2bf(-2.f * hi[2]); a[7] = (short)f2bf(-2.f * hi[3]);
      Af[mi][ks] = a;
    }
    nrm += __shfl_xor(nrm, 16);  // sum across the 4 quads (full 64-dim norm)
    nrm += __shfl_xor(nrm, 32);
    if (quad == 0) xn[waveRow0 + mi * 16 + col] = nrm;
  }

  unsigned bk[4][4];
#pragma unroll
  for (int mi = 0; mi < 4; ++mi)
#pragma unroll
    for (int r = 0; r < 4; ++r) bk[mi][r] = 0xFFFFFFFFu;

  __syncthreads();  // codebook staged (vmcnt drained), c2s/xn visible

  // ---- Barrier-free K-loop: 64 iters x 16 codes. LDS + MFMA + VALU only.
  // unroll 8: ~8 independent ds_read->MFMA->min chains in flight (VGPR<=256).
  const unsigned short* bbase = cbs + (size_t)col * CSTRIDE + quad * 8;
#pragma unroll 8
  for (int t = 0; t < 64; ++t) {
    const unsigned short* bp = bbase + t * 16 * CSTRIDE;
    short8 b0 = *(const short8*)bp;
    short8 b1 = *(const short8*)(bp + 32);
    float cc = c2s[t * 16 + col];

    f32x4 acc[4];
#pragma unroll
    for (int mi = 0; mi < 4; ++mi) {
      f32x4 a = {cc, cc, cc, cc};
      a = __builtin_amdgcn_mfma_f32_16x16x32_bf16(Af[mi][0], b0, a, 0, 0, 0);
      a = __builtin_amdgcn_mfma_f32_16x16x32_bf16(Af[mi][1], b1, a, 0, 0, 0);
      acc[mi] = a;
    }

    const unsigned code = (unsigned)((t << 4) + col);
#pragma unroll
    for (int mi = 0; mi < 4; ++mi)
#pragma unroll
      for (int r = 0; r < 4; ++r)
        bk[mi][r] = min(bk[mi][r], (__float_as_uint(acc[mi][r]) & 0xFFFFFC00u) | code);
  }

  // ---- Reduce keys across the 16 columns of each quad group.
#pragma unroll
  for (int off = 1; off < 16; off <<= 1) {
#pragma unroll
    for (int mi = 0; mi < 4; ++mi)
#pragma unroll
      for (int r = 0; r < 4; ++r) {
        unsigned o = (unsigned)__shfl_xor((int)bk[mi][r], off);
        bk[mi][r] = min(bk[mi][r], o);
      }
  }

  // ---- Indices + SSE from the packed keys (no output pass, no x re-read).
  float sse = 0.f;
  if (col == 0) {
#pragma unroll
    for (int mi = 0; mi < 4; ++mi)
#pragma unroll
      for (int r = 0; r < 4; ++r) {
        const int row = waveRow0 + mi * 16 + quad * 4 + r;
        gidx[blockRow0 + row] = (int)(bk[mi][r] & 1023u);
        const float s_rec = __uint_as_float(bk[mi][r] & 0xFFFFFC00u);
        sse += s_rec - 0.5f + xn[row];
      }
  }
  sse += __shfl_xor(sse, 16);  // sum the 4 quads' col==0 lanes
  sse += __shfl_xor(sse, 32);
  if (lane == 0) redbuf[wave] = sse;
  __syncthreads();

  if (tid == 0) {
    float s = 0.f;
#pragma unroll
    for (int w = 0; w < 8; ++w) s += redbuf[w];
    atomicAdd(sse_out, s);
    __threadfence();
    unsigned old = atomicAdd(counter, 1u);
    if (old == (unsigned)(nblocks - 1)) {
      float tot = atomicAdd(sse_out, 0.f);
      long nelem = (long)nblocks * MTILE * VQ_D;
      out[nelem] = 1.25f * tot / (float)nelem;
    }
  }
}

// Pure streaming scatter: out row = exact fp32 codebook row. Hoisted idx
// loads, nontemporal stores (no L2 pollution; full-line streaming writes).
__global__ __launch_bounds__(256) void vq_gather(const float* __restrict__ cb,
                                                 const int* __restrict__ gidx,
                                                 float* __restrict__ out) {
  const int t = blockIdx.x * 256 + threadIdx.x;  // 2^19 threads
  const f32x4* cb4 = (const f32x4*)cb;
  f32x4* out4 = (f32x4*)out;
  int idx[4];
#pragma unroll
  for (int i = 0; i < 4; ++i) idx[i] = gidx[(t + i * (1 << 19)) >> 4];
  f32x4 cv[4];
#pragma unroll
  for (int i = 0; i < 4; ++i) {
    const int d4 = (t + i * (1 << 19)) & 15;
    cv[i] = cb4[(size_t)idx[i] * 16 + d4];
  }
#pragma unroll
  for (int i = 0; i < 4; ++i)
    __builtin_nontemporal_store(cv[i], &out4[t + i * (1 << 19)]);
}

extern "C" void kernel_launch(void* const* d_in, const int* in_sizes, int n_in,
                              void* d_out, int out_size, void* d_ws, size_t ws_size,
                              hipStream_t stream) {
  const float* x = (const float*)d_in[0];
  const float* cb = (const float*)d_in[1];
  float* out = (float*)d_out;

  const long n_elem = (long)in_sizes[0];   // 8388608
  const int nrows = (int)(n_elem / VQ_D);  // 131072
  const int K = in_sizes[1] / VQ_D;        // 1024
  const int nblocks = nrows / MTILE;       // 256

  char* ws = (char*)d_ws;
  float* sse = (float*)ws;                             // 4 B
  unsigned* counter = (unsigned*)(ws + 64);            // 4 B
  float* c2b = (float*)(ws + 256);                     // 4 KB
  unsigned short* cbb = (unsigned short*)(ws + 8192);  // 139264 B padded bf16 codebook
  int* gidx = (int*)(ws + 8192 + 139264);              // 512 KB row indices

  vq_prep<<<dim3((K * 64 + 255) / 256), dim3(256), 0, stream>>>(cb, c2b, cbb, sse, counter, K);
  vq_argmin<<<dim3(nblocks), dim3(NTH), 0, stream>>>(x, c2b, cbb, gidx, out, sse, counter, nblocks);
  vq_gather<<<dim3(nrows * 16 / (256 * 4)), dim3(256), 0, stream>>>(cb, gidx, out);
}